// Round 5
// baseline (541.193 us; speedup 1.0000x reference)
//
#include <hip/hip_runtime.h>
#include <stdint.h>

// Problem constants
#define BB 16
#define CC 512
#define CQK 64
#define NN 1024   // H*W = 32*32
#define NBLK 640  // fused grid size

typedef __attribute__((ext_vector_type(8))) short bf16x8;
typedef __attribute__((ext_vector_type(4))) short short4v;
typedef __attribute__((ext_vector_type(4))) float f32x4;

static __device__ __forceinline__ unsigned short f2bf(float f) {
  uint32_t u = __float_as_uint(f);
  u += 0x7FFFu + ((u >> 16) & 1u);
  return (unsigned short)(u >> 16);
}

// Async global->LDS, 16B per lane. LDS dest = wave-uniform base + lane*16.
static __device__ __forceinline__ void gll16(const unsigned short* g, unsigned short* l) {
  const __attribute__((address_space(1))) unsigned int* gp =
      reinterpret_cast<const __attribute__((address_space(1))) unsigned int*>(
          reinterpret_cast<uintptr_t>(g));
  __attribute__((address_space(3))) unsigned int* lp =
      reinterpret_cast<__attribute__((address_space(3))) unsigned int*>(
          (unsigned int)reinterpret_cast<uintptr_t>(l));
  __builtin_amdgcn_global_load_lds(gp, lp, 16, 0, 0);
}

// ---------------------------------------------------------------------------
// Software grid barrier (graph-capture-safe; no cooperative launch).
// Monotonic ticket counter in module .data (zero at load): correct across
// graph replays / rocprof re-runs without any reset. All NBLK blocks are
// co-resident by construction (LDS 32KB -> 5/CU; launch_bounds(256,4) caps
// VGPR<=128 -> 4/CU; need only 3/CU), so the spin cannot deadlock; a
// bounded spin turns a violated assumption into a wrong answer, not a hang.
// ---------------------------------------------------------------------------
__device__ unsigned int g_bar = 0;

static __device__ __forceinline__ void gridbar() {
  __syncthreads();
  __threadfence();  // release: flush this block's writes past XCD L2
  if (threadIdx.x == 0) {
    unsigned int ticket =
        __hip_atomic_fetch_add(&g_bar, 1u, __ATOMIC_RELAXED, __HIP_MEMORY_SCOPE_AGENT);
    unsigned int target = (ticket / NBLK + 1u) * NBLK;
    unsigned int spins = 0;
    while (__hip_atomic_load(&g_bar, __ATOMIC_RELAXED, __HIP_MEMORY_SCOPE_AGENT) < target) {
      __builtin_amdgcn_s_sleep(4);
      if (++spins > (1u << 20)) break;  // safety valve
    }
  }
  __syncthreads();
  __threadfence();  // acquire: invalidate stale cache lines before next phase
}

#define QT 64
#define MC 64
#define PSTR 72  // ushort units; 144B row stride (16B-aligned, 2-way banks = free)

// ---------------------------------------------------------------------------
// ONE kernel, 640 blocks x 256 threads, 3 phases split by software gridbar.
// Eliminates ~40 us of inter-dispatch overhead (R0-R3: kernel-time sum ~113
// us vs wall 166-178 us).
//   Phase A: pack W (blocks<320) + transpose x->xT (grid-stride 8192 tiles).
//   Phase B: GEMM1 (R1-proven xT body), 640 tiles 1:1, XCD-swizzled.
//   Phase C: flash (R3-proven body, af1 hoisted), blocks<512, XCD-swizzled.
// LDS: 32 KB union.
// ---------------------------------------------------------------------------
__global__ __launch_bounds__(256, 4) void k_fused(
    const float* __restrict__ x,
    const float* __restrict__ Wq, const float* __restrict__ bq,
    const float* __restrict__ Wk, const float* __restrict__ bk,
    const float* __restrict__ Wv, const float* __restrict__ bv,
    const float* __restrict__ gamma,
    unsigned short* __restrict__ Wall, unsigned short* __restrict__ xT,
    unsigned short* __restrict__ qkT, unsigned short* __restrict__ vbuf,
    float* __restrict__ out) {
  __shared__ __align__(16) char lds_raw[32768];

  int bid = blockIdx.x;
  int t = threadIdx.x;

  // ===================== Phase A: pack + transpose =====================
  if (bid < 320) {
    int e = (bid * 256 + t) * 4;
    int o = e >> 9;
    int c = e & 511;
    const float* src;
    if (o < 64)        src = Wq + (size_t)o * 512;
    else if (o < 128)  src = Wk + (size_t)(o - 64) * 512;
    else               src = Wv + (size_t)(o - 128) * 512;
    float4 v = *(const float4*)(src + c);
    short4v pk;
    pk[0] = (short)f2bf(v.x); pk[1] = (short)f2bf(v.y);
    pk[2] = (short)f2bf(v.z); pk[3] = (short)f2bf(v.w);
    *(short4v*)(Wall + e) = pk;
  }

  {
    float (*tile)[33] = (float (*)[33])lds_raw;  // 32*33*4 = 4224 B
    int tn = t & 31, tc = t >> 5;  // tc 0..7
    for (int tau = bid; tau < 8192; tau += NBLK) {
      int bz = tau >> 9;           // b
      int by = (tau >> 5) & 15;    // c-tile
      int bx = tau & 31;           // n-tile
      int c0 = by * 32, n0 = bx * 32;
      const float* xp = x + ((size_t)bz * CC + c0) * NN + n0;
#pragma unroll
      for (int i = 0; i < 4; i++) {
        int c = tc + i * 8;
        tile[c][tn] = xp[(size_t)c * NN + tn];
      }
      __syncthreads();
      unsigned short* xq = xT + ((size_t)bz * NN + n0) * CC + c0;
      int n = t >> 3;
      int cq = (t & 7) * 4;
      short4v pk;
#pragma unroll
      for (int k = 0; k < 4; k++) pk[k] = (short)f2bf(tile[cq + k][n]);
      *(short4v*)(&xq[(size_t)n * CC + cq]) = pk;
      __syncthreads();  // LDS reuse in next iteration
    }
  }

  gridbar();

  // ===================== Phase B: GEMM1 (R1 body) =====================
  {
    unsigned short* ldsA = (unsigned short*)lds_raw;   // 2 x 4096 ushorts
    unsigned short* ldsB = ldsA + 8192;                // 2 x 4096 ushorts
    // XCD-aware swizzle: hw block h -> logical tile (h%8)*80 + h/8 (640=8*80)
    int swz = (bid & 7) * 80 + (bid >> 3);
    int nx = swz & 7;
    int rest = swz >> 3;
    int oy = rest % 5;
    int b = rest / 5;
    int o0 = oy * 128;
    int n0 = nx * 128;
    int w = t >> 6, l = t & 63;
    int wm = w & 1, wn = w >> 1;
    int lr = l & 15, lq = l >> 4;

    f32x4 acc[4][4];
#pragma unroll
    for (int i = 0; i < 4; i++)
#pragma unroll
      for (int j = 0; j < 4; j++) acc[i][j] = (f32x4){0.f, 0.f, 0.f, 0.f};

    const unsigned short* Ab = Wall + (size_t)o0 * CC;
    const unsigned short* Bb = xT + ((size_t)b * NN + n0) * CC;
    int srow = t >> 2;          // 0..63
    int skq = (t & 3) * 8;      // bf16 offset within 32-wide k tile
    int ldsw = (t >> 6) * 512;  // wave-uniform LDS base (ushort units)

    // Prologue: stage k-tile 0 into buffer 0.
#pragma unroll
    for (int p = 0; p < 2; p++) {
      int r = p * 64 + srow;
      gll16(&Ab[(size_t)r * CC + skq], &ldsA[p * 2048 + ldsw]);
      gll16(&Bb[(size_t)r * CC + skq], &ldsB[p * 2048 + ldsw]);
    }
    __syncthreads();

    for (int s = 0; s < 16; ++s) {
      int cur = s & 1;
      if (s + 1 < 16) {
        int kt = (s + 1) * 32;
#pragma unroll
        for (int p = 0; p < 2; p++) {
          int r = p * 64 + srow;
          gll16(&Ab[(size_t)r * CC + kt + skq], &ldsA[(cur ^ 1) * 4096 + p * 2048 + ldsw]);
          gll16(&Bb[(size_t)r * CC + kt + skq], &ldsB[(cur ^ 1) * 4096 + p * 2048 + ldsw]);
        }
      }
      bf16x8 af[4], bfr[4];
#pragma unroll
      for (int i = 0; i < 4; i++)
        af[i] = *(const bf16x8*)(&ldsA[cur * 4096 + (wm * 64 + i * 16 + lr) * 32 + lq * 8]);
#pragma unroll
      for (int j = 0; j < 4; j++)
        bfr[j] = *(const bf16x8*)(&ldsB[cur * 4096 + (wn * 64 + j * 16 + lr) * 32 + lq * 8]);
#pragma unroll
      for (int i = 0; i < 4; i++)
#pragma unroll
        for (int j = 0; j < 4; j++)
          acc[i][j] = __builtin_amdgcn_mfma_f32_16x16x32_bf16(af[i], bfr[j], acc[i][j], 0, 0, 0);
      __syncthreads();
    }

    if (o0 == 0) {
#pragma unroll
      for (int i = 0; i < 4; i++) {
        int ob = wm * 64 + i * 16 + lq * 4;
#pragma unroll
        for (int j = 0; j < 4; j++) {
          int n = n0 + wn * 64 + j * 16 + lr;
          short4v pk;
#pragma unroll
          for (int r = 0; r < 4; r++) {
            int o = ob + r;
            float bias = (o < 64) ? bq[o] : bk[o - 64];
            pk[r] = (short)f2bf(acc[i][j][r] + bias);
          }
          *(short4v*)(&qkT[((size_t)b * NN + n) * 128 + ob]) = pk;
        }
      }
    } else {
#pragma unroll
      for (int i = 0; i < 4; i++) {
#pragma unroll
        for (int r = 0; r < 4; r++) {
          int o = o0 + wm * 64 + i * 16 + lq * 4 + r;
          int c = o - 128;
          float bias = bv[c];
#pragma unroll
          for (int j = 0; j < 4; j++) {
            int n = n0 + wn * 64 + j * 16 + lr;
            vbuf[((size_t)b * CC + c) * NN + n] = f2bf(acc[i][j][r] + bias);
          }
        }
      }
    }
  }

  gridbar();

  // ===================== Phase C: flash (R3 body) =====================
  if (bid < 512) {
    unsigned short* P = (unsigned short*)lds_raw;       // 9216 B
    float* red = (float*)(lds_raw + 9216);              // 1024 B
    float* fin = (float*)(lds_raw + 9216 + 1024);       // 256 B

    // XCD-aware swizzle: hw block h -> logical (h%8)*64 + h/8 (512 = 8*64).
    int swz = (bid & 7) * 64 + (bid >> 3);
    int ntile = swz & 15;
    int chalf = (swz >> 4) & 1;
    int b = swz >> 5;
    int n0 = ntile * QT;
    int w = t >> 6, l = t & 63;
    int lr = l & 15, lq = l >> 4;
    const unsigned short* qk = qkT + (size_t)b * NN * 128;
    const unsigned short* Vb = vbuf + ((size_t)b * CC + chalf * 256 + w * 64) * NN;

    // Q fragments (constant over all chunks)
    bf16x8 aq[4][2];
#pragma unroll
    for (int nj = 0; nj < 4; nj++)
#pragma unroll
      for (int ks = 0; ks < 2; ks++)
        aq[nj][ks] = *(const bf16x8*)(&qk[(size_t)(n0 + nj * 16 + lr) * 128 + ks * 32 + lq * 8]);

    f32x4 acc[4][4];  // [ci][nj]
#pragma unroll
    for (int ci = 0; ci < 4; ci++)
#pragma unroll
      for (int nj = 0; nj < 4; nj++) acc[ci][nj] = (f32x4){0.f, 0.f, 0.f, 0.f};
    float sreg[4][4];
#pragma unroll
    for (int nj = 0; nj < 4; nj++)
#pragma unroll
      for (int r = 0; r < 4; r++) sreg[nj][r] = 0.f;

    // Prologue: scores+exp for chunk 0
    float ev[4][4];
    {
      int mrow = w * 16 + lr;  // m0 = 0
      bf16x8 kf0 = *(const bf16x8*)(&qk[(size_t)mrow * 128 + 64 + lq * 8]);
      bf16x8 kf1 = *(const bf16x8*)(&qk[(size_t)mrow * 128 + 96 + lq * 8]);
#pragma unroll
      for (int nj = 0; nj < 4; nj++) {
        f32x4 s = (f32x4){0.f, 0.f, 0.f, 0.f};
        s = __builtin_amdgcn_mfma_f32_16x16x32_bf16(aq[nj][0], kf0, s, 0, 0, 0);
        s = __builtin_amdgcn_mfma_f32_16x16x32_bf16(aq[nj][1], kf1, s, 0, 0, 0);
#pragma unroll
        for (int r = 0; r < 4; r++) {
          float e = __expf(s[r]);
          ev[nj][r] = e;
          sreg[nj][r] += e;
        }
      }
    }

    for (int m0 = 0; m0 < NN; m0 += MC) {
      // Prefetch V fragments for BOTH ks of this chunk (af1 hoisted).
      bf16x8 af0[4], af1[4];
#pragma unroll
      for (int ci = 0; ci < 4; ci++)
        af0[ci] = *(const bf16x8*)(&Vb[(size_t)(ci * 16 + lr) * NN + m0 + lq * 8]);
#pragma unroll
      for (int ci = 0; ci < 4; ci++)
        af1[ci] = *(const bf16x8*)(&Vb[(size_t)(ci * 16 + lr) * NN + m0 + 32 + lq * 8]);

      // Prefetch next-chunk K fragments early (consumed after barrier 1).
      bf16x8 kf0n, kf1n;
      if (m0 + MC < NN) {
        int mrow = m0 + MC + w * 16 + lr;
        kf0n = *(const bf16x8*)(&qk[(size_t)mrow * 128 + 64 + lq * 8]);
        kf1n = *(const bf16x8*)(&qk[(size_t)mrow * 128 + 96 + lq * 8]);
      }

      __syncthreads();  // all PV reads of previous chunk's P complete
#pragma unroll
      for (int nj = 0; nj < 4; nj++)
#pragma unroll
        for (int r = 0; r < 4; r++)
          P[(nj * 16 + lq * 4 + r) * PSTR + w * 16 + lr] = f2bf(ev[nj][r]);

      // Compute scores+exp for NEXT chunk while P settles.
      if (m0 + MC < NN) {
#pragma unroll
        for (int nj = 0; nj < 4; nj++) {
          f32x4 s = (f32x4){0.f, 0.f, 0.f, 0.f};
          s = __builtin_amdgcn_mfma_f32_16x16x32_bf16(aq[nj][0], kf0n, s, 0, 0, 0);
          s = __builtin_amdgcn_mfma_f32_16x16x32_bf16(aq[nj][1], kf1n, s, 0, 0, 0);
#pragma unroll
          for (int r = 0; r < 4; r++) {
            float e = __expf(s[r]);
            ev[nj][r] = e;
            sreg[nj][r] += e;
          }
        }
      }
      __syncthreads();  // P ready

      // PV ks=0
#pragma unroll
      for (int nj = 0; nj < 4; nj++) {
        bf16x8 pf = *(const bf16x8*)(&P[(nj * 16 + lr) * PSTR + lq * 8]);
#pragma unroll
        for (int ci = 0; ci < 4; ci++)
          acc[ci][nj] = __builtin_amdgcn_mfma_f32_16x16x32_bf16(af0[ci], pf, acc[ci][nj], 0, 0, 0);
      }
      // PV ks=1
#pragma unroll
      for (int nj = 0; nj < 4; nj++) {
        bf16x8 pf = *(const bf16x8*)(&P[(nj * 16 + lr) * PSTR + 32 + lq * 8]);
#pragma unroll
        for (int ci = 0; ci < 4; ci++)
          acc[ci][nj] = __builtin_amdgcn_mfma_f32_16x16x32_bf16(af1[ci], pf, acc[ci][nj], 0, 0, 0);
      }
    }

    // ---- final row sums (across 16 lr lanes, then 4 waves) ----
#pragma unroll
    for (int nj = 0; nj < 4; nj++)
#pragma unroll
      for (int r = 0; r < 4; r++) {
#pragma unroll
        for (int d = 1; d < 16; d <<= 1) sreg[nj][r] += __shfl_xor(sreg[nj][r], d, 64);
      }
    __syncthreads();
    if (lr == 0) {
#pragma unroll
      for (int nj = 0; nj < 4; nj++)
#pragma unroll
        for (int r = 0; r < 4; r++) red[w * QT + nj * 16 + lq * 4 + r] = sreg[nj][r];
    }
    __syncthreads();
    if (t < QT) {
      float ssum = red[t] + red[QT + t] + red[2 * QT + t] + red[3 * QT + t];
      fin[t] = ssum;
    }
    __syncthreads();

    float invL[4];
#pragma unroll
    for (int nj = 0; nj < 4; nj++) invL[nj] = 1.0f / fin[nj * 16 + lr];
    float g = gamma[0];
#pragma unroll
    for (int ci = 0; ci < 4; ci++) {
#pragma unroll
      for (int r = 0; r < 4; r++) {
        int c = chalf * 256 + w * 64 + ci * 16 + lq * 4 + r;
#pragma unroll
        for (int nj = 0; nj < 4; nj++) {
          size_t idx = ((size_t)b * CC + c) * NN + n0 + nj * 16 + lr;
          out[idx] = g * acc[ci][nj][r] * invL[nj] + x[idx];
        }
      }
    }
  }
}

// ---------------------------------------------------------------------------
extern "C" void kernel_launch(void* const* d_in, const int* in_sizes, int n_in,
                              void* d_out, int out_size, void* d_ws, size_t ws_size,
                              hipStream_t stream) {
  (void)in_sizes; (void)n_in; (void)out_size; (void)ws_size;
  const float* x     = (const float*)d_in[0];
  const float* Wq    = (const float*)d_in[1];
  const float* bq    = (const float*)d_in[2];
  const float* Wk    = (const float*)d_in[3];
  const float* bk    = (const float*)d_in[4];
  const float* Wv    = (const float*)d_in[5];
  const float* bv    = (const float*)d_in[6];
  const float* gamma = (const float*)d_in[7];
  float* out = (float*)d_out;

  char* ws = (char*)d_ws;
  unsigned short* Wall = (unsigned short*)(ws);                       // 655,360 B
  unsigned short* xT   = (unsigned short*)(ws + 655360);              // 16,777,216 B
  unsigned short* qkT  = (unsigned short*)(ws + 655360 + 16777216);   // 4,194,304 B
  unsigned short* vbuf = (unsigned short*)(ws + 655360 + 16777216 + 4194304);  // 16,777,216 B
  // total ~38.4 MB

  k_fused<<<dim3(NBLK), dim3(256), 0, stream>>>(
      x, Wq, bq, Wk, bk, Wv, bv, gamma, Wall, xT, qkT, vbuf, out);
}

// Round 6
// 165.473 us; speedup vs baseline: 3.2706x; 3.2706x over previous
//
#include <hip/hip_runtime.h>
#include <stdint.h>

// Problem constants
#define BB 16
#define CC 512
#define CQK 64
#define NN 1024   // H*W = 32*32

typedef __attribute__((ext_vector_type(8))) short bf16x8;
typedef __attribute__((ext_vector_type(4))) short short4v;
typedef __attribute__((ext_vector_type(4))) float f32x4;

static __device__ __forceinline__ unsigned short f2bf(float f) {
  uint32_t u = __float_as_uint(f);
  u += 0x7FFFu + ((u >> 16) & 1u);
  return (unsigned short)(u >> 16);
}

// Async global->LDS, 16B per lane. LDS dest = wave-uniform base + lane*16.
static __device__ __forceinline__ void gll16(const unsigned short* g, unsigned short* l) {
  const __attribute__((address_space(1))) unsigned int* gp =
      reinterpret_cast<const __attribute__((address_space(1))) unsigned int*>(
          reinterpret_cast<uintptr_t>(g));
  __attribute__((address_space(3))) unsigned int* lp =
      reinterpret_cast<__attribute__((address_space(3))) unsigned int*>(
          (unsigned int)reinterpret_cast<uintptr_t>(l));
  __builtin_amdgcn_global_load_lds(gp, lp, 16, 0, 0);
}

// ---------------------------------------------------------------------------
// Kernel 1: transpose x[b][c][n] (fp32) -> xT[b][n][c] (bf16)
//   + first 320 blocks also pack Wq|Wk|Wv -> bf16 Wall[640][512]
//   (R2-proven phase-A body; fusing pack drops one launch ~15 us).
// grid (N/32, C/32, B), block 256
// ---------------------------------------------------------------------------
__global__ __launch_bounds__(256) void k_prep(
    const float* __restrict__ x, unsigned short* __restrict__ xT,
    const float* __restrict__ Wq, const float* __restrict__ Wk,
    const float* __restrict__ Wv, unsigned short* __restrict__ Wall) {
  __shared__ float tile[32][33];
  int b = blockIdx.z;
  int c0 = blockIdx.y * 32;
  int n0 = blockIdx.x * 32;
  int t = threadIdx.x;

  // fused weight pack (640*512 / 4 / 256 = 320 blocks)
  int flat = ((int)blockIdx.z * gridDim.y + blockIdx.y) * gridDim.x + blockIdx.x;
  if (flat < 320) {
    int e = (flat * 256 + t) * 4;
    int o = e >> 9;
    int c = e & 511;
    const float* src;
    if (o < 64)        src = Wq + (size_t)o * 512;
    else if (o < 128)  src = Wk + (size_t)(o - 64) * 512;
    else               src = Wv + (size_t)(o - 128) * 512;
    float4 v = *(const float4*)(src + c);
    short4v pk;
    pk[0] = (short)f2bf(v.x); pk[1] = (short)f2bf(v.y);
    pk[2] = (short)f2bf(v.z); pk[3] = (short)f2bf(v.w);
    *(short4v*)(Wall + e) = pk;
  }

  int tn = t & 31, tc = t >> 5;  // tc 0..7
  const float* xp = x + ((size_t)b * CC + c0) * NN + n0;
#pragma unroll
  for (int i = 0; i < 4; i++) {
    int c = tc + i * 8;
    tile[c][tn] = xp[(size_t)c * NN + tn];
  }
  __syncthreads();
  unsigned short* xq = xT + ((size_t)b * NN + n0) * CC + c0;
  int n = t >> 3;
  int cq = (t & 7) * 4;
  short4v pk;
#pragma unroll
  for (int k = 0; k < 4; k++) pk[k] = (short)f2bf(tile[cq + k][n]);
  *(short4v*)(&xq[(size_t)n * CC + cq]) = pk;
}

// ---------------------------------------------------------------------------
// Kernel 2: GEMM1  D[o][n] = sum_c Wall[o][c] * xT[b][n][c]  + bias
//   (R1-proven body, unchanged.)
//   o<128 -> qkT[b][n][o] (transposed store), o>=128 -> vbuf[b][o-128][n].
// 1-D grid of 640 blocks (logical (nx,oy,b) = (8,5,16)), 256 threads.
// XCD-swizzled; LDS double-buffered, stage(k+1) before compute(k).
// ---------------------------------------------------------------------------
__global__ __launch_bounds__(256) void k_gemm1(
    const unsigned short* __restrict__ Wall, const unsigned short* __restrict__ xT,
    const float* __restrict__ bq, const float* __restrict__ bk,
    const float* __restrict__ bv,
    unsigned short* __restrict__ qkT, unsigned short* __restrict__ vbuf) {
  __shared__ __align__(16) unsigned short ldsA[2][128 * 32];
  __shared__ __align__(16) unsigned short ldsB[2][128 * 32];
  int bid = blockIdx.x;
  int swz = (bid & 7) * 80 + (bid >> 3);
  int nx = swz & 7;
  int rest = swz >> 3;
  int oy = rest % 5;
  int b = rest / 5;
  int o0 = oy * 128;
  int n0 = nx * 128;
  int t = threadIdx.x;
  int w = t >> 6, l = t & 63;
  int wm = w & 1, wn = w >> 1;
  int lr = l & 15, lq = l >> 4;

  f32x4 acc[4][4];
#pragma unroll
  for (int i = 0; i < 4; i++)
#pragma unroll
    for (int j = 0; j < 4; j++) acc[i][j] = (f32x4){0.f, 0.f, 0.f, 0.f};

  const unsigned short* Ab = Wall + (size_t)o0 * CC;
  const unsigned short* Bb = xT + ((size_t)b * NN + n0) * CC;
  int srow = t >> 2;
  int skq = (t & 3) * 8;
  int ldsw = (t >> 6) * 512;

#pragma unroll
  for (int p = 0; p < 2; p++) {
    int r = p * 64 + srow;
    gll16(&Ab[(size_t)r * CC + skq], &ldsA[0][p * 2048 + ldsw]);
    gll16(&Bb[(size_t)r * CC + skq], &ldsB[0][p * 2048 + ldsw]);
  }
  __syncthreads();

  for (int s = 0; s < 16; ++s) {
    int cur = s & 1;
    if (s + 1 < 16) {
      int kt = (s + 1) * 32;
#pragma unroll
      for (int p = 0; p < 2; p++) {
        int r = p * 64 + srow;
        gll16(&Ab[(size_t)r * CC + kt + skq], &ldsA[cur ^ 1][p * 2048 + ldsw]);
        gll16(&Bb[(size_t)r * CC + kt + skq], &ldsB[cur ^ 1][p * 2048 + ldsw]);
      }
    }
    bf16x8 af[4], bfr[4];
#pragma unroll
    for (int i = 0; i < 4; i++)
      af[i] = *(const bf16x8*)(&ldsA[cur][(wm * 64 + i * 16 + lr) * 32 + lq * 8]);
#pragma unroll
    for (int j = 0; j < 4; j++)
      bfr[j] = *(const bf16x8*)(&ldsB[cur][(wn * 64 + j * 16 + lr) * 32 + lq * 8]);
#pragma unroll
    for (int i = 0; i < 4; i++)
#pragma unroll
      for (int j = 0; j < 4; j++)
        acc[i][j] = __builtin_amdgcn_mfma_f32_16x16x32_bf16(af[i], bfr[j], acc[i][j], 0, 0, 0);
    __syncthreads();
  }

  if (o0 == 0) {
#pragma unroll
    for (int i = 0; i < 4; i++) {
      int ob = wm * 64 + i * 16 + lq * 4;
#pragma unroll
      for (int j = 0; j < 4; j++) {
        int n = n0 + wn * 64 + j * 16 + lr;
        short4v pk;
#pragma unroll
        for (int r = 0; r < 4; r++) {
          int o = ob + r;
          float bias = (o < 64) ? bq[o] : bk[o - 64];
          pk[r] = (short)f2bf(acc[i][j][r] + bias);
        }
        *(short4v*)(&qkT[((size_t)b * NN + n) * 128 + ob]) = pk;
      }
    }
  } else {
#pragma unroll
    for (int i = 0; i < 4; i++) {
#pragma unroll
      for (int r = 0; r < 4; r++) {
        int o = o0 + wm * 64 + i * 16 + lq * 4 + r;
        int c = o - 128;
        float bias = bv[c];
#pragma unroll
        for (int j = 0; j < 4; j++) {
          int n = n0 + wn * 64 + j * 16 + lr;
          vbuf[((size_t)b * CC + c) * NN + n] = f2bf(acc[i][j][r] + bias);
        }
      }
    }
  }
}

// ---------------------------------------------------------------------------
// Kernel 3: one-pass flash, R1 structure (512 blocks, 2-way c-split,
//   acc[4][4]) with a CHUNK-DEEP register pipeline:
//   - V-ks0 and K fragments are loaded one full chunk ahead (consumed a
//     whole iteration after issue -> L3 miss latency (~600-900cy) covered).
//   - V-ks1 loaded at chunk top (covered by P-write + S-compute + 2 barriers).
//   Rationale: R1 counters showed all pipes ~15% at 2 blocks/CU and per-XCD
//   working set (qkT+vbuf ~5MB) > 4MB L2 -> latency-bound on L3 hits.
//   VGPR ~210 is fine: occupancy is grid-capped at 2 waves/SIMD (<=256).
// ---------------------------------------------------------------------------
#define QT 64
#define MC 64
#define PSTR 72  // ushort units; 144B row stride (16B-aligned, 2-way banks = free)

__global__ __launch_bounds__(256, 2) void k_flash(
    const unsigned short* __restrict__ qkT, const unsigned short* __restrict__ vbuf,
    const float* __restrict__ x, const float* __restrict__ gamma,
    float* __restrict__ out) {
  __shared__ __align__(16) unsigned short P[QT * PSTR];  // 9216 B
  __shared__ float red[4 * QT];                          // 1024 B
  __shared__ float fin[QT];                              // 256 B

  // XCD-aware swizzle: hw block h -> logical id (h%8)*64 + h/8 (512 = 8*64).
  int bid = blockIdx.x;
  int swz = (bid & 7) * 64 + (bid >> 3);
  int ntile = swz & 15;
  int chalf = (swz >> 4) & 1;
  int b = swz >> 5;
  int n0 = ntile * QT;
  int t = threadIdx.x;
  int w = t >> 6, l = t & 63;
  int lr = l & 15, lq = l >> 4;
  int lq8 = lq * 8;
  const unsigned short* qk = qkT + (size_t)b * NN * 128;
  const unsigned short* Vb = vbuf + ((size_t)b * CC + chalf * 256 + w * 64) * NN;

  // Q fragments (constant over all chunks)
  bf16x8 aq[4][2];
#pragma unroll
  for (int nj = 0; nj < 4; nj++)
#pragma unroll
    for (int ks = 0; ks < 2; ks++)
      aq[nj][ks] = *(const bf16x8*)(&qk[(size_t)(n0 + nj * 16 + lr) * 128 + ks * 32 + lq8]);

  f32x4 acc[4][4];  // [ci][nj]
#pragma unroll
  for (int ci = 0; ci < 4; ci++)
#pragma unroll
    for (int nj = 0; nj < 4; nj++) acc[ci][nj] = (f32x4){0.f, 0.f, 0.f, 0.f};
  float sreg[4][4];
#pragma unroll
  for (int nj = 0; nj < 4; nj++)
#pragma unroll
    for (int r = 0; r < 4; r++) sreg[nj][r] = 0.f;

  // Prologue:
  //   ev    = exp(S) for chunk 0
  //   vA    = V ks0 fragments for chunk 0
  //   kf*c  = K fragments for chunk MC (consumed during iteration m0=0)
  bf16x8 vA[4];
#pragma unroll
  for (int ci = 0; ci < 4; ci++)
    vA[ci] = *(const bf16x8*)(&Vb[(size_t)(ci * 16 + lr) * NN + lq8]);
  bf16x8 kf0c, kf1c;
  {
    int mrow = MC + w * 16 + lr;
    kf0c = *(const bf16x8*)(&qk[(size_t)mrow * 128 + 64 + lq8]);
    kf1c = *(const bf16x8*)(&qk[(size_t)mrow * 128 + 96 + lq8]);
  }
  float ev[4][4];
  {
    int mrow = w * 16 + lr;  // m0 = 0
    bf16x8 kf0 = *(const bf16x8*)(&qk[(size_t)mrow * 128 + 64 + lq8]);
    bf16x8 kf1 = *(const bf16x8*)(&qk[(size_t)mrow * 128 + 96 + lq8]);
#pragma unroll
    for (int nj = 0; nj < 4; nj++) {
      f32x4 s = (f32x4){0.f, 0.f, 0.f, 0.f};
      s = __builtin_amdgcn_mfma_f32_16x16x32_bf16(aq[nj][0], kf0, s, 0, 0, 0);
      s = __builtin_amdgcn_mfma_f32_16x16x32_bf16(aq[nj][1], kf1, s, 0, 0, 0);
#pragma unroll
      for (int r = 0; r < 4; r++) {
        float e = __expf(s[r]);
        ev[nj][r] = e;
        sreg[nj][r] += e;
      }
    }
  }

  for (int m0 = 0; m0 < NN; m0 += MC) {
    bool hn = (m0 + MC < NN);
    // Current-chunk V ks1 (consumed after barrier2 + PV ks0; covered by
    // P-write + S-compute + both barriers).
    bf16x8 vB[4];
#pragma unroll
    for (int ci = 0; ci < 4; ci++)
      vB[ci] = *(const bf16x8*)(&Vb[(size_t)(ci * 16 + lr) * NN + m0 + 32 + lq8]);
    // NEXT-chunk V ks0 (consumed one full iteration from now).
    bf16x8 vAn[4];
    if (hn) {
#pragma unroll
      for (int ci = 0; ci < 4; ci++)
        vAn[ci] = *(const bf16x8*)(&Vb[(size_t)(ci * 16 + lr) * NN + m0 + MC + lq8]);
    }
    // K for chunk m0+2*MC (consumed next iteration's S-compute).
    bf16x8 kf0n, kf1n;
    if (m0 + 2 * MC < NN) {
      int mrow = m0 + 2 * MC + w * 16 + lr;
      kf0n = *(const bf16x8*)(&qk[(size_t)mrow * 128 + 64 + lq8]);
      kf1n = *(const bf16x8*)(&qk[(size_t)mrow * 128 + 96 + lq8]);
    }

    __syncthreads();  // all PV reads of previous chunk's P complete
#pragma unroll
    for (int nj = 0; nj < 4; nj++)
#pragma unroll
      for (int r = 0; r < 4; r++)
        P[(nj * 16 + lq * 4 + r) * PSTR + w * 16 + lr] = f2bf(ev[nj][r]);

    // Scores+exp for NEXT chunk (K was loaded one iteration ago).
    if (hn) {
#pragma unroll
      for (int nj = 0; nj < 4; nj++) {
        f32x4 s = (f32x4){0.f, 0.f, 0.f, 0.f};
        s = __builtin_amdgcn_mfma_f32_16x16x32_bf16(aq[nj][0], kf0c, s, 0, 0, 0);
        s = __builtin_amdgcn_mfma_f32_16x16x32_bf16(aq[nj][1], kf1c, s, 0, 0, 0);
#pragma unroll
        for (int r = 0; r < 4; r++) {
          float e = __expf(s[r]);
          ev[nj][r] = e;
          sreg[nj][r] += e;
        }
      }
    }
    __syncthreads();  // P ready

    // PV ks=0 (vA loaded one full iteration ago)
#pragma unroll
    for (int nj = 0; nj < 4; nj++) {
      bf16x8 pf = *(const bf16x8*)(&P[(nj * 16 + lr) * PSTR + lq8]);
#pragma unroll
      for (int ci = 0; ci < 4; ci++)
        acc[ci][nj] = __builtin_amdgcn_mfma_f32_16x16x32_bf16(vA[ci], pf, acc[ci][nj], 0, 0, 0);
    }
    // PV ks=1
#pragma unroll
    for (int nj = 0; nj < 4; nj++) {
      bf16x8 pf = *(const bf16x8*)(&P[(nj * 16 + lr) * PSTR + 32 + lq8]);
#pragma unroll
      for (int ci = 0; ci < 4; ci++)
        acc[ci][nj] = __builtin_amdgcn_mfma_f32_16x16x32_bf16(vB[ci], pf, acc[ci][nj], 0, 0, 0);
    }

    if (hn) {
#pragma unroll
      for (int ci = 0; ci < 4; ci++) vA[ci] = vAn[ci];
      kf0c = kf0n;
      kf1c = kf1n;
    }
  }

  // ---- final row sums (across 16 lr lanes, then 4 waves) ----
#pragma unroll
  for (int nj = 0; nj < 4; nj++)
#pragma unroll
    for (int r = 0; r < 4; r++) {
#pragma unroll
      for (int d = 1; d < 16; d <<= 1) sreg[nj][r] += __shfl_xor(sreg[nj][r], d, 64);
    }
  __syncthreads();
  if (lr == 0) {
#pragma unroll
    for (int nj = 0; nj < 4; nj++)
#pragma unroll
      for (int r = 0; r < 4; r++) red[w * QT + nj * 16 + lq * 4 + r] = sreg[nj][r];
  }
  __syncthreads();
  if (t < QT) {
    float ssum = red[t] + red[QT + t] + red[2 * QT + t] + red[3 * QT + t];
    fin[t] = ssum;
  }
  __syncthreads();

  float invL[4];
#pragma unroll
  for (int nj = 0; nj < 4; nj++) invL[nj] = 1.0f / fin[nj * 16 + lr];
  float g = gamma[0];
#pragma unroll
  for (int ci = 0; ci < 4; ci++) {
#pragma unroll
    for (int r = 0; r < 4; r++) {
      int c = chalf * 256 + w * 64 + ci * 16 + lq * 4 + r;
#pragma unroll
      for (int nj = 0; nj < 4; nj++) {
        size_t idx = ((size_t)b * CC + c) * NN + n0 + nj * 16 + lr;
        out[idx] = g * acc[ci][nj][r] * invL[nj] + x[idx];
      }
    }
  }
}

// ---------------------------------------------------------------------------
extern "C" void kernel_launch(void* const* d_in, const int* in_sizes, int n_in,
                              void* d_out, int out_size, void* d_ws, size_t ws_size,
                              hipStream_t stream) {
  (void)in_sizes; (void)n_in; (void)out_size; (void)ws_size;
  const float* x     = (const float*)d_in[0];
  const float* Wq    = (const float*)d_in[1];
  const float* bq    = (const float*)d_in[2];
  const float* Wk    = (const float*)d_in[3];
  const float* bk    = (const float*)d_in[4];
  const float* Wv    = (const float*)d_in[5];
  const float* bv    = (const float*)d_in[6];
  const float* gamma = (const float*)d_in[7];
  float* out = (float*)d_out;

  char* ws = (char*)d_ws;
  unsigned short* Wall = (unsigned short*)(ws);                       // 655,360 B
  unsigned short* xT   = (unsigned short*)(ws + 655360);              // 16,777,216 B
  unsigned short* qkT  = (unsigned short*)(ws + 655360 + 16777216);   // 4,194,304 B
  unsigned short* vbuf = (unsigned short*)(ws + 655360 + 16777216 + 4194304);  // 16,777,216 B
  // total ~38.4 MB

  k_prep<<<dim3(NN / 32, CC / 32, BB), dim3(256), 0, stream>>>(x, xT, Wq, Wk, Wv, Wall);
  k_gemm1<<<dim3(640), dim3(256), 0, stream>>>(Wall, xT, bq, bk, bv, qkT, vbuf);
  k_flash<<<dim3(512), dim3(256), 0, stream>>>(qkT, vbuf, x, gamma, out);
}